// Round 14
// baseline (1033.446 us; speedup 1.0000x reference)
//
#include <hip/hip_runtime.h>
#include <cstddef>

#define NS 512
#define NL 5
#define NT 20
#define NE 768
#define NH 64
#define NG 256   // 4*H
#define DUMMY_FL 16777216   // 64 MB float offset into workspace for dup writes

__device__ __forceinline__ float sigf(float x) { return 1.0f / (1.0f + expf(-x)); }

typedef __fp16 h16x2 __attribute__((ext_vector_type(2)));
typedef _Float16 f16x8 __attribute__((ext_vector_type(8)));
typedef __attribute__((ext_vector_type(4))) float f32x4;

union PkU { h16x2 h; unsigned u; };
union FrU { uint4 u4; f16x8 h8; };

__device__ __forceinline__ void split_pk(float a, float b, unsigned& hi, unsigned& lo) {
    PkU H, L;
    H.h = __builtin_amdgcn_cvt_pkrtz(a, b);
    float ra = a - (float)H.h[0];
    float rb = b - (float)H.h[1];
    L.h = __builtin_amdgcn_cvt_pkrtz(ra, rb);
    hi = H.u; lo = L.u;
}

__device__ __forceinline__ void pack8(const float v[8], uint4& ph, uint4& pl) {
    split_pk(v[0], v[1], ph.x, pl.x);
    split_pk(v[2], v[3], ph.y, pl.y);
    split_pk(v[4], v[5], ph.z, pl.z);
    split_pk(v[6], v[7], ph.w, pl.w);
}

__device__ __forceinline__ void stage8(const float v[8], unsigned short* base, unsigned off) {
    uint4 ph, pl;
    pack8(v, ph, pl);
    *(uint4*)&base[off]       = ph;
    *(uint4*)&base[off + 512] = pl;
}

// ---------------------------------------------------------------------------
// Kernel 1 v7 (measured 129.3 us; unchanged).
// ---------------------------------------------------------------------------
__global__ __launch_bounds__(512, 4) void k_gemm_u(
    const float* __restrict__ x, const float* __restrict__ U,
    const float* __restrict__ bU, float* __restrict__ u)
{
    __shared__ unsigned short Af[8 * 2 * 512];   // 16 KB
    __shared__ unsigned short Bf[8 * 2 * 512];   // 16 KB
    const int bid = blockIdx.x;
    const int s = bid >> 1, half = bid & 1;
    const int tid = threadIdx.x;
    const int wave = tid >> 6, lane = tid & 63;
    const int wm = wave & 1, wn = wave >> 1;
    const float* xg = x + (size_t)s * (NL * NT * NE);
    const float* Ug = U + (size_t)s * (NE * NG) + half * 128;

    f32x4 acc[4][2] = {};

    const int arow = tid >> 2, ab = tid & 3;
    const unsigned a_off = ((unsigned)(arow >> 4) * 2) * 512 + ((arow & 15) + 16 * ab) * 8;
    const int bcol = tid & 127, bkq = tid >> 7;
    const unsigned b_off = ((unsigned)(bcol >> 4) * 2) * 512 + ((bcol & 15) + 16 * bkq) * 8;

    float av[8], bv[8];
    {
        const float* pa = xg + (size_t)arow * NE + ab * 8;
        if (arow < 100) {
            float4 q0 = *(const float4*)pa, q1 = *(const float4*)(pa + 4);
            av[0]=q0.x; av[1]=q0.y; av[2]=q0.z; av[3]=q0.w;
            av[4]=q1.x; av[5]=q1.y; av[6]=q1.z; av[7]=q1.w;
        } else {
            #pragma unroll
            for (int j = 0; j < 8; ++j) av[j] = 0.0f;
        }
        #pragma unroll
        for (int j = 0; j < 8; ++j)
            bv[j] = Ug[(size_t)(8 * bkq + j) * NG + bcol];
    }

    for (int st = 0; st < 24; ++st) {
        stage8(av, Af, a_off);
        stage8(bv, Bf, b_off);
        __syncthreads();

        if (st + 1 < 24) {
            const int k0 = (st + 1) * 32;
            const float* pa = xg + (size_t)arow * NE + k0 + ab * 8;
            if (arow < 100) {
                float4 q0 = *(const float4*)pa, q1 = *(const float4*)(pa + 4);
                av[0]=q0.x; av[1]=q0.y; av[2]=q0.z; av[3]=q0.w;
                av[4]=q1.x; av[5]=q1.y; av[6]=q1.z; av[7]=q1.w;
            } else {
                #pragma unroll
                for (int j = 0; j < 8; ++j) av[j] = 0.0f;
            }
            #pragma unroll
            for (int j = 0; j < 8; ++j)
                bv[j] = Ug[(size_t)(k0 + 8 * bkq + j) * NG + bcol];
        }

        f16x8 bh[2], bl[2];
        #pragma unroll
        for (int ni = 0; ni < 2; ++ni) {
            const unsigned nt = wn * 2 + ni;
            bh[ni] = *(const f16x8*)&Bf[(nt * 2 + 0) * 512 + lane * 8];
            bl[ni] = *(const f16x8*)&Bf[(nt * 2 + 1) * 512 + lane * 8];
        }
        #pragma unroll
        for (int mi = 0; mi < 4; ++mi) {
            const unsigned mt = wm * 4 + mi;
            f16x8 ah = *(const f16x8*)&Af[(mt * 2 + 0) * 512 + lane * 8];
            f16x8 al = *(const f16x8*)&Af[(mt * 2 + 1) * 512 + lane * 8];
            #pragma unroll
            for (int ni = 0; ni < 2; ++ni) {
                acc[mi][ni] = __builtin_amdgcn_mfma_f32_16x16x32_f16(ah, bh[ni], acc[mi][ni], 0, 0, 0);
                acc[mi][ni] = __builtin_amdgcn_mfma_f32_16x16x32_f16(ah, bl[ni], acc[mi][ni], 0, 0, 0);
                acc[mi][ni] = __builtin_amdgcn_mfma_f32_16x16x32_f16(al, bh[ni], acc[mi][ni], 0, 0, 0);
            }
        }
        __syncthreads();
    }

    const int c_sub = 4 * (lane >> 4);
    #pragma unroll
    for (int ni = 0; ni < 2; ++ni) {
        const int gcol = half * 128 + (wn * 2 + ni) * 16 + (lane & 15);
        const float bb = bU[(size_t)s * NG + gcol];
        #pragma unroll
        for (int mi = 0; mi < 4; ++mi) {
            const int grow0 = wm * 64 + mi * 16 + c_sub;
            #pragma unroll
            for (int r = 0; r < 4; ++r) {
                const int grow = grow0 + r;
                if (grow < 100) {
                    const int ld = grow / 20, td = grow % 20;
                    u[(((size_t)s * NT + td) * NL + ld) * NG + gcol] = acc[mi][ni][r] + bb;
                }
            }
        }
    }
}

// ---------------------------------------------------------------------------
// Kernel 2a v4 body UNCHANGED. ROUND 14 MEASUREMENT: grid = 5*NS; dup blocks
// (bid>=NS) recompute the same stock but write to a dummy workspace region
// (+64 MB) -> one ~480us dispatch lands in the top-5 WITH counters
// (VGPR/spill via WRITE_SIZE, occupancy, VALUBusy, bank conflicts).
// Real blocks (dup==0) are byte-identical to round-13 behavior.
// ---------------------------------------------------------------------------
__global__ __launch_bounds__(512, 4) void k_recur(
    float* __restrict__ u, const float* __restrict__ ti,
    const float* __restrict__ Wall, const float* __restrict__ bWall,
    const float* __restrict__ Wd, const float* __restrict__ bWd)
{
    __shared__ float GATES[NL * NG];   // 5 KB
    __shared__ float WDC[NL * NH];     // 1.25 KB
    __shared__ float HSP[NL * 68];
    __shared__ float CSP[NL * 68];
    __shared__ float TSH[NL * NT];

    const int s = (int)(blockIdx.x & (NS - 1));
    const int dup = (int)(blockIdx.x >> 9);
    const int tid = threadIdx.x;
    const int wave = tid >> 6, lane = tid & 63;
    const float* ug = u + (size_t)s * NT * NL * NG;                 // reads
    float* ugw = (dup ? u + DUMMY_FL : u) + (size_t)s * NT * NL * NG; // writes

    for (int i = tid; i < NL * 68; i += 512) { HSP[i] = 0.0f; CSP[i] = 0.0f; }
    if (tid < NL * NT) TSH[tid] = ti[(size_t)s * NL * NT + tid];

    const int nT = (wave < 4) ? 3 : 2;
    f16x8 Bh[3][2], Bl[3][2];
    {
        const float* Wg = Wall + (size_t)s * (NH * NG);
        const float* Dg = Wd + (size_t)s * (NH * NH);
        const int fcol = lane & 15, foct = lane >> 4;
        #pragma unroll
        for (int t2 = 0; t2 < 3; ++t2) {
            if (t2 < nT) {
                const int tc = wave + t2 * 8;
                #pragma unroll
                for (int ks = 0; ks < 2; ++ks) {
                    float v[8];
                    if (tc < 16) {
                        #pragma unroll
                        for (int j = 0; j < 8; ++j)
                            v[j] = Wg[(size_t)(ks * 32 + foct * 8 + j) * NG + tc * 16 + fcol];
                    } else {
                        #pragma unroll
                        for (int j = 0; j < 8; ++j)
                            v[j] = Dg[(size_t)(ks * 32 + foct * 8 + j) * NH + (tc - 16) * 16 + fcol];
                    }
                    FrU H, L;
                    pack8(v, H.u4, L.u4);
                    Bh[t2][ks] = H.h8;
                    Bl[t2][ks] = L.h8;
                }
            }
        }
    }

    const int lq = tid >> 6, hh = tid & 63;
    float bw[4], bwd_r = 0.0f, un[4], c_reg = 0.0f, h_reg = 0.0f;
    if (tid < 320) {
        #pragma unroll
        for (int j = 0; j < 4; ++j) {
            bw[j] = bWall[(size_t)s * NG + j * 64 + hh];
            un[j] = ug[(size_t)(0 * NL + lq) * NG + j * 64 + hh];
        }
        bwd_r = bWd[(size_t)s * NH + hh];
    }
    __syncthreads();

    const int arow = lane & 15, akq = lane >> 4;
    for (int t = 0; t < NT; ++t) {
        f16x8 ah[2], al[2], cah[2], cal[2];
        #pragma unroll
        for (int ks = 0; ks < 2; ++ks) {
            float v[8];
            if (arow < NL) {
                float4 q0 = *(const float4*)&HSP[arow * 68 + ks * 32 + akq * 8];
                float4 q1 = *(const float4*)&HSP[arow * 68 + ks * 32 + akq * 8 + 4];
                v[0]=q0.x; v[1]=q0.y; v[2]=q0.z; v[3]=q0.w;
                v[4]=q1.x; v[5]=q1.y; v[6]=q1.z; v[7]=q1.w;
            } else {
                #pragma unroll
                for (int j = 0; j < 8; ++j) v[j] = 0.0f;
            }
            FrU H, L;
            pack8(v, H.u4, L.u4);
            ah[ks] = H.h8; al[ks] = L.h8;
        }
        if (wave < 4) {
            #pragma unroll
            for (int ks = 0; ks < 2; ++ks) {
                float v[8];
                if (arow < NL) {
                    float4 q0 = *(const float4*)&CSP[arow * 68 + ks * 32 + akq * 8];
                    float4 q1 = *(const float4*)&CSP[arow * 68 + ks * 32 + akq * 8 + 4];
                    v[0]=q0.x; v[1]=q0.y; v[2]=q0.z; v[3]=q0.w;
                    v[4]=q1.x; v[5]=q1.y; v[6]=q1.z; v[7]=q1.w;
                } else {
                    #pragma unroll
                    for (int j = 0; j < 8; ++j) v[j] = 0.0f;
                }
                FrU H, L;
                pack8(v, H.u4, L.u4);
                cah[ks] = H.h8; cal[ks] = L.h8;
            }
        }
        #pragma unroll
        for (int t2 = 0; t2 < 3; ++t2) {
            if (t2 < nT) {
                const int tc = wave + t2 * 8;
                const bool isWd = (tc >= 16);
                f32x4 acc = {};
                #pragma unroll
                for (int ks = 0; ks < 2; ++ks) {
                    f16x8 A_h = isWd ? cah[ks] : ah[ks];
                    f16x8 A_l = isWd ? cal[ks] : al[ks];
                    acc = __builtin_amdgcn_mfma_f32_16x16x32_f16(A_h, Bh[t2][ks], acc, 0, 0, 0);
                    acc = __builtin_amdgcn_mfma_f32_16x16x32_f16(A_h, Bl[t2][ks], acc, 0, 0, 0);
                    acc = __builtin_amdgcn_mfma_f32_16x16x32_f16(A_l, Bh[t2][ks], acc, 0, 0, 0);
                }
                #pragma unroll
                for (int r = 0; r < 4; ++r) {
                    const int row = 4 * akq + r;
                    if (row < NL) {
                        if (!isWd) GATES[row * NG + tc * 16 + arow] = acc[r];
                        else       WDC[row * NH + (tc - 16) * 16 + arow] = acc[r];
                    }
                }
            }
        }
        float unx[4];
        if (tid < 320 && t + 1 < NT) {
            #pragma unroll
            for (int j = 0; j < 4; ++j)
                unx[j] = ug[(size_t)((t + 1) * NL + lq) * NG + j * 64 + hh];
        }
        __syncthreads();

        if (tid < 320) {
            float g0 = GATES[lq * NG + hh]        + bw[0] + un[0];
            float g1 = GATES[lq * NG + 64 + hh]   + bw[1] + un[1];
            float g2 = GATES[lq * NG + 128 + hh]  + bw[2] + un[2];
            float g3 = GATES[lq * NG + 192 + hh]  + bw[3] + un[3];
            float f  = sigf(g0), ii = sigf(g1), oo = sigf(g2), ct = sigf(g3);
            float cs1 = tanhf(WDC[lq * NH + hh] + bwd_r);
            float ca  = c_reg - cs1 + cs1 * TSH[lq * NT + t];
            float cn  = f * ca + ii * ct;
            c_reg = cn;
            h_reg = oo * tanhf(cn);
            HSP[lq * 68 + hh] = h_reg;
            CSP[lq * 68 + hh] = cn;
            ugw[(size_t)(t * NL + lq) * NG + hh] = oo;   // o_t (dup -> dummy)
            #pragma unroll
            for (int j = 0; j < 4; ++j) un[j] = unx[j];
        }
        __syncthreads();
    }
    if (tid < 320)
        ugw[(size_t)(0 * NL + lq) * NG + 64 + hh] = h_reg;   // h_fin (dup -> dummy)
}

// ---------------------------------------------------------------------------
// Kernel 2b (unchanged): attention + day LSTM + head. Measured 62.8 us.
// ---------------------------------------------------------------------------
#define P_W1    0
#define P_W2    4096
#define P_FULLO 8192
#define P_HS    14592
#define P_TQ    14912
#define P_CA    15232
#define P_SC    15552
#define P_B0    15652
#define P_B1    15716
#define P_BVV   15780
#define P_BV1   15844
#define P_TOT   15848

__global__ __launch_bounds__(320, 2) void k_post(
    const float* __restrict__ u,
    const float* __restrict__ W1, const float* __restrict__ b1,
    const float* __restrict__ W2, const float* __restrict__ b2,
    const float* __restrict__ V, const float* __restrict__ bV,
    const float* __restrict__ Wih, const float* __restrict__ bih,
    const float* __restrict__ bhh, const float* __restrict__ lin_w,
    const float* __restrict__ lin_b, float* __restrict__ out)
{
    __shared__ float sm[P_TOT];
    const int s = blockIdx.x;
    const int tid = threadIdx.x;
    const int lq = tid >> 6, hh = tid & 63;
    const int lane = hh;
    const float* ug = u + (size_t)s * NT * NL * NG;

    for (int i = tid; i < 1024; i += 320)
        *(float4*)&sm[P_W1 + i * 4] = *(const float4*)(W1 + (size_t)s * 4096 + i * 4);
    for (int i = tid; i < 1024; i += 320)
        *(float4*)&sm[P_W2 + i * 4] = *(const float4*)(W2 + (size_t)s * 4096 + i * 4);
    for (int i = tid; i < 1600; i += 320) {
        const int idx = i >> 4;
        const int l = idx / NT, t = idx % NT;
        const int k4 = (i & 15) * 4;
        *(float4*)&sm[P_FULLO + idx * NH + k4] =
            *(const float4*)(ug + (size_t)(t * NL + l) * NG + k4);
    }
    sm[P_HS + tid] = ug[(size_t)(0 * NL + lq) * NG + 64 + hh];
    if (tid < NH) {
        sm[P_B0 + tid]  = b1[(size_t)s * NH + tid];
        sm[P_B1 + tid]  = b2[(size_t)s * NH + tid];
        sm[P_BVV + tid] = V[(size_t)s * NH + tid];
    }
    if (tid == 0) sm[P_BV1] = bV[s];
    __syncthreads();

    {
        float qv = sm[P_B0 + hh];
        for (int k4 = 0; k4 < NH; k4 += 4) {
            float4 hv = *(const float4*)&sm[P_HS + lq * NH + k4];
            qv += hv.x * sm[P_W1 + (k4 + 0) * NH + hh]
                + hv.y * sm[P_W1 + (k4 + 1) * NH + hh]
                + hv.z * sm[P_W1 + (k4 + 2) * NH + hh]
                + hv.w * sm[P_W1 + (k4 + 3) * NH + hh];
        }
        sm[P_TQ + tid] = qv;
    }
    __syncthreads();

    for (int lt = lq; lt < NL * NT; lt += 5) {
        int l = lt / NT;
        float v = sm[P_TQ + l * NH + lane] + sm[P_B1 + lane];
        for (int k4 = 0; k4 < NH; k4 += 4) {
            float4 fv = *(const float4*)&sm[P_FULLO + lt * NH + k4];
            v += fv.x * sm[P_W2 + (k4 + 0) * NH + lane]
               + fv.y * sm[P_W2 + (k4 + 1) * NH + lane]
               + fv.z * sm[P_W2 + (k4 + 2) * NH + lane]
               + fv.w * sm[P_W2 + (k4 + 3) * NH + lane];
        }
        v = tanhf(v) * sm[P_BVV + lane];
        #pragma unroll
        for (int m = 32; m > 0; m >>= 1) v += __shfl_xor(v, m, 64);
        if (lane == 0) sm[P_SC + lt] = v + sm[P_BV1];
    }
    __syncthreads();

    if (tid < NL) {
        float mx = -1e30f;
        for (int t = 0; t < NT; ++t) mx = fmaxf(mx, sm[P_SC + tid * NT + t]);
        float sum = 0.0f;
        for (int t = 0; t < NT; ++t) {
            float e = expf(sm[P_SC + tid * NT + t] - mx);
            sm[P_SC + tid * NT + t] = e;
            sum += e;
        }
        float inv = 1.0f / sum;
        for (int t = 0; t < NT; ++t) sm[P_SC + tid * NT + t] *= inv;
    }
    __syncthreads();

    {
        float sv = 0.0f;
        #pragma unroll
        for (int t = 0; t < NT; ++t)
            sv += sm[P_SC + lq * NT + t] * sm[P_FULLO + (lq * NT + t) * NH + hh];
        sm[P_CA + tid] = sv;
    }
    __syncthreads();

    if (tid < NG) {
        float bsum = bih[(size_t)s * NG + tid] + bhh[(size_t)s * NG + tid];
        float d[NL];
        #pragma unroll
        for (int l = 0; l < NL; ++l) d[l] = bsum;
        for (int k = 0; k < NH; ++k) {
            float wk = Wih[((size_t)s * NH + k) * NG + tid];
            #pragma unroll
            for (int l = 0; l < NL; ++l)
                d[l] += sm[P_CA + l * NH + k] * wk;
        }
        #pragma unroll
        for (int l = 0; l < NL; ++l)
            sm[P_FULLO + l * NG + tid] = d[l];
    }
    __syncthreads();
    {
        float gi = sm[P_FULLO + lq * NG + hh];
        float gg = sm[P_FULLO + lq * NG + 128 + hh];
        float go = sm[P_FULLO + lq * NG + 192 + hh];
        float cd = sigf(gi) * tanhf(gg);
        sm[P_TQ + tid] = sigf(go) * tanhf(cd);
    }
    __syncthreads();

    {
        float v = sm[P_B0 + lane] + sm[P_B1 + lane];
        for (int k4 = 0; k4 < NH; k4 += 4) {
            float4 hv = *(const float4*)&sm[P_TQ + lq * NH + k4];
            v += hv.x * (sm[P_W1 + (k4 + 0) * NH + lane] + sm[P_W2 + (k4 + 0) * NH + lane])
               + hv.y * (sm[P_W1 + (k4 + 1) * NH + lane] + sm[P_W2 + (k4 + 1) * NH + lane])
               + hv.z * (sm[P_W1 + (k4 + 2) * NH + lane] + sm[P_W2 + (k4 + 2) * NH + lane])
               + hv.w * (sm[P_W1 + (k4 + 3) * NH + lane] + sm[P_W2 + (k4 + 3) * NH + lane]);
        }
        v = tanhf(v) * sm[P_BVV + lane];
        #pragma unroll
        for (int m = 32; m > 0; m >>= 1) v += __shfl_xor(v, m, 64);
        if (lane == 0) sm[P_SC + lq] = v + sm[P_BV1];
    }
    __syncthreads();
    if (tid == 0) {
        float mx = -1e30f;
        for (int l = 0; l < NL; ++l) mx = fmaxf(mx, sm[P_SC + l]);
        float sum = 0.0f;
        for (int l = 0; l < NL; ++l) {
            float e = expf(sm[P_SC + l] - mx);
            sm[P_SC + l] = e;
            sum += e;
        }
        float inv = 1.0f / sum;
        for (int l = 0; l < NL; ++l) sm[P_SC + l] *= inv;
    }
    __syncthreads();

    if (tid < NH) {
        float fv = 0.0f;
        #pragma unroll
        for (int l = 0; l < NL; ++l)
            fv += sm[P_SC + l] * sm[P_TQ + l * NH + tid];
        fv *= lin_w[tid];
        #pragma unroll
        for (int m = 32; m > 0; m >>= 1) fv += __shfl_xor(fv, m, 64);
        if (tid == 0) {
            float val = fv + lin_b[0];
            out[s] = val > 0.0f ? val : 0.01f * val;
        }
    }
}

extern "C" void kernel_launch(void* const* d_in, const int* in_sizes, int n_in,
                              void* d_out, int out_size, void* d_ws, size_t ws_size,
                              hipStream_t stream) {
    (void)in_sizes; (void)n_in; (void)out_size; (void)ws_size;
    const float* x     = (const float*)d_in[0];
    const float* ti    = (const float*)d_in[1];
    const float* Wall  = (const float*)d_in[2];
    const float* bWall = (const float*)d_in[3];
    const float* Uall  = (const float*)d_in[4];
    const float* bUall = (const float*)d_in[5];
    const float* Wd    = (const float*)d_in[6];
    const float* bWd   = (const float*)d_in[7];
    const float* W1    = (const float*)d_in[8];
    const float* b1    = (const float*)d_in[9];
    const float* W2    = (const float*)d_in[10];
    const float* b2    = (const float*)d_in[11];
    const float* V     = (const float*)d_in[12];
    const float* bV    = (const float*)d_in[13];
    const float* Wih   = (const float*)d_in[14];
    const float* bih   = (const float*)d_in[16];
    const float* bhh   = (const float*)d_in[17];
    const float* lin_w = (const float*)d_in[18];
    const float* lin_b = (const float*)d_in[19];
    float* out = (float*)d_out;
    float* u = (float*)d_ws;   // [S][T][L][NG] = 52.4 MB; dummy region at +64 MB

    k_gemm_u<<<NS * 2, 512, 0, stream>>>(x, Uall, bUall, u);
    // ROUND 14 MEASUREMENT: 5x grid; dup blocks write to dummy region so the
    // recur dispatch (~480us) enters the top-5 counter table.
    k_recur<<<NS * 5, 512, 0, stream>>>(u, ti, Wall, bWall, Wd, bWd);
    k_post<<<NS, 320, 0, stream>>>(u, W1, b1, W2, b2, V, bV,
                                   Wih, bih, bhh, lin_w, lin_b, out);
}

// Round 15
// 831.778 us; speedup vs baseline: 1.2425x; 1.2425x over previous
//
#include <hip/hip_runtime.h>
#include <cstddef>

#define NS 512
#define NL 5
#define NT 20
#define NE 768
#define NH 64
#define NG 256   // 4*H

__device__ __forceinline__ float sigf(float x) { return 1.0f / (1.0f + expf(-x)); }

typedef __fp16 h16x2 __attribute__((ext_vector_type(2)));
typedef _Float16 f16x8 __attribute__((ext_vector_type(8)));
typedef __attribute__((ext_vector_type(4))) float f32x4;

union PkU { h16x2 h; unsigned u; };
union U16 { __fp16 f; unsigned short s; };

__device__ __forceinline__ void split_pk(float a, float b, unsigned& hi, unsigned& lo) {
    PkU H, L;
    H.h = __builtin_amdgcn_cvt_pkrtz(a, b);
    float ra = a - (float)H.h[0];
    float rb = b - (float)H.h[1];
    L.h = __builtin_amdgcn_cvt_pkrtz(ra, rb);
    hi = H.u; lo = L.u;
}

__device__ __forceinline__ void pack8(const float v[8], uint4& ph, uint4& pl) {
    split_pk(v[0], v[1], ph.x, pl.x);
    split_pk(v[2], v[3], ph.y, pl.y);
    split_pk(v[4], v[5], ph.z, pl.z);
    split_pk(v[6], v[7], ph.w, pl.w);
}

__device__ __forceinline__ void stage8(const float v[8], unsigned short* base, unsigned off) {
    uint4 ph, pl;
    pack8(v, ph, pl);
    *(uint4*)&base[off]       = ph;
    *(uint4*)&base[off + 512] = pl;
}

// ---------------------------------------------------------------------------
// Kernel 1 v7 (measured 129.3 us; unchanged).
// ---------------------------------------------------------------------------
__global__ __launch_bounds__(512, 4) void k_gemm_u(
    const float* __restrict__ x, const float* __restrict__ U,
    const float* __restrict__ bU, float* __restrict__ u)
{
    __shared__ unsigned short Af[8 * 2 * 512];   // 16 KB
    __shared__ unsigned short Bf[8 * 2 * 512];   // 16 KB
    const int bid = blockIdx.x;
    const int s = bid >> 1, half = bid & 1;
    const int tid = threadIdx.x;
    const int wave = tid >> 6, lane = tid & 63;
    const int wm = wave & 1, wn = wave >> 1;
    const float* xg = x + (size_t)s * (NL * NT * NE);
    const float* Ug = U + (size_t)s * (NE * NG) + half * 128;

    f32x4 acc[4][2] = {};

    const int arow = tid >> 2, ab = tid & 3;
    const unsigned a_off = ((unsigned)(arow >> 4) * 2) * 512 + ((arow & 15) + 16 * ab) * 8;
    const int bcol = tid & 127, bkq = tid >> 7;
    const unsigned b_off = ((unsigned)(bcol >> 4) * 2) * 512 + ((bcol & 15) + 16 * bkq) * 8;

    float av[8], bv[8];
    {
        const float* pa = xg + (size_t)arow * NE + ab * 8;
        if (arow < 100) {
            float4 q0 = *(const float4*)pa, q1 = *(const float4*)(pa + 4);
            av[0]=q0.x; av[1]=q0.y; av[2]=q0.z; av[3]=q0.w;
            av[4]=q1.x; av[5]=q1.y; av[6]=q1.z; av[7]=q1.w;
        } else {
            #pragma unroll
            for (int j = 0; j < 8; ++j) av[j] = 0.0f;
        }
        #pragma unroll
        for (int j = 0; j < 8; ++j)
            bv[j] = Ug[(size_t)(8 * bkq + j) * NG + bcol];
    }

    for (int st = 0; st < 24; ++st) {
        stage8(av, Af, a_off);
        stage8(bv, Bf, b_off);
        __syncthreads();

        if (st + 1 < 24) {
            const int k0 = (st + 1) * 32;
            const float* pa = xg + (size_t)arow * NE + k0 + ab * 8;
            if (arow < 100) {
                float4 q0 = *(const float4*)pa, q1 = *(const float4*)(pa + 4);
                av[0]=q0.x; av[1]=q0.y; av[2]=q0.z; av[3]=q0.w;
                av[4]=q1.x; av[5]=q1.y; av[6]=q1.z; av[7]=q1.w;
            } else {
                #pragma unroll
                for (int j = 0; j < 8; ++j) av[j] = 0.0f;
            }
            #pragma unroll
            for (int j = 0; j < 8; ++j)
                bv[j] = Ug[(size_t)(k0 + 8 * bkq + j) * NG + bcol];
        }

        f16x8 bh[2], bl[2];
        #pragma unroll
        for (int ni = 0; ni < 2; ++ni) {
            const unsigned nt = wn * 2 + ni;
            bh[ni] = *(const f16x8*)&Bf[(nt * 2 + 0) * 512 + lane * 8];
            bl[ni] = *(const f16x8*)&Bf[(nt * 2 + 1) * 512 + lane * 8];
        }
        #pragma unroll
        for (int mi = 0; mi < 4; ++mi) {
            const unsigned mt = wm * 4 + mi;
            f16x8 ah = *(const f16x8*)&Af[(mt * 2 + 0) * 512 + lane * 8];
            f16x8 al = *(const f16x8*)&Af[(mt * 2 + 1) * 512 + lane * 8];
            #pragma unroll
            for (int ni = 0; ni < 2; ++ni) {
                acc[mi][ni] = __builtin_amdgcn_mfma_f32_16x16x32_f16(ah, bh[ni], acc[mi][ni], 0, 0, 0);
                acc[mi][ni] = __builtin_amdgcn_mfma_f32_16x16x32_f16(ah, bl[ni], acc[mi][ni], 0, 0, 0);
                acc[mi][ni] = __builtin_amdgcn_mfma_f32_16x16x32_f16(al, bh[ni], acc[mi][ni], 0, 0, 0);
            }
        }
        __syncthreads();
    }

    const int c_sub = 4 * (lane >> 4);
    #pragma unroll
    for (int ni = 0; ni < 2; ++ni) {
        const int gcol = half * 128 + (wn * 2 + ni) * 16 + (lane & 15);
        const float bb = bU[(size_t)s * NG + gcol];
        #pragma unroll
        for (int mi = 0; mi < 4; ++mi) {
            const int grow0 = wm * 64 + mi * 16 + c_sub;
            #pragma unroll
            for (int r = 0; r < 4; ++r) {
                const int grow = grow0 + r;
                if (grow < 100) {
                    const int ld = grow / 20, td = grow % 20;
                    u[(((size_t)s * NT + td) * NL + ld) * NG + gcol] = acc[mi][ni][r] + bb;
                }
            }
        }
    }
}

// ---------------------------------------------------------------------------
// Kernel 2a v5: state kept PRE-SPLIT as fp16 hi/lo in LDS. Round-14 counters
// showed v4 VALU-bound (67.7% VALUBusy, MFMA 15%): every wave re-ran pack8 on
// the same h/c fragments each step (~100 VALU/thread/step, 8x redundant).
// Now phase 2's 320 threads convert once (4 VALU each: cvt,sub,cvt) into
// HSH/HSL/CSH/CSL ushort[16][72] (rows 5..15 zeroed once = zero-padding;
// +8 pad de-aligns row stride from banks); phase 1 assembles A-frags with
// plain ds_read_b128 -- ZERO conversion VALU in the hot loop.
// ---------------------------------------------------------------------------
#define RSTRIDE 72

__global__ __launch_bounds__(512, 4) void k_recur(
    float* __restrict__ u, const float* __restrict__ ti,
    const float* __restrict__ Wall, const float* __restrict__ bWall,
    const float* __restrict__ Wd, const float* __restrict__ bWd)
{
    __shared__ float GATES[NL * NG];            // 5 KB
    __shared__ float WDC[NL * NH];              // 1.25 KB
    __shared__ unsigned short HSH[16 * RSTRIDE];
    __shared__ unsigned short HSL[16 * RSTRIDE];
    __shared__ unsigned short CSH[16 * RSTRIDE];
    __shared__ unsigned short CSL[16 * RSTRIDE];
    __shared__ float TSH[NL * NT];

    const int s = blockIdx.x;
    const int tid = threadIdx.x;
    const int wave = tid >> 6, lane = tid & 63;
    float* ug = u + (size_t)s * NT * NL * NG;

    for (int i = tid; i < 16 * RSTRIDE; i += 512) {
        HSH[i] = 0; HSL[i] = 0; CSH[i] = 0; CSL[i] = 0;
    }
    if (tid < NL * NT) TSH[tid] = ti[(size_t)s * NL * NT + tid];

    // ---- B-fragments directly global -> registers (once) ----
    const int nT = (wave < 4) ? 3 : 2;
    f16x8 Bh[3][2], Bl[3][2];
    {
        const float* Wg = Wall + (size_t)s * (NH * NG);
        const float* Dg = Wd + (size_t)s * (NH * NH);
        const int fcol = lane & 15, foct = lane >> 4;
        #pragma unroll
        for (int t2 = 0; t2 < 3; ++t2) {
            if (t2 < nT) {
                const int tc = wave + t2 * 8;
                #pragma unroll
                for (int ks = 0; ks < 2; ++ks) {
                    float v[8];
                    if (tc < 16) {
                        #pragma unroll
                        for (int j = 0; j < 8; ++j)
                            v[j] = Wg[(size_t)(ks * 32 + foct * 8 + j) * NG + tc * 16 + fcol];
                    } else {
                        #pragma unroll
                        for (int j = 0; j < 8; ++j)
                            v[j] = Dg[(size_t)(ks * 32 + foct * 8 + j) * NH + (tc - 16) * 16 + fcol];
                    }
                    union { uint4 u4; f16x8 h8; } H, L;
                    pack8(v, H.u4, L.u4);
                    Bh[t2][ks] = H.h8;
                    Bl[t2][ks] = L.h8;
                }
            }
        }
    }

    // ---- consumer state (tid<320): (l,hh) item ----
    const int lq = tid >> 6, hh = tid & 63;
    float bw[4], bwd_r = 0.0f, un[4], c_reg = 0.0f, h_reg = 0.0f;
    if (tid < 320) {
        #pragma unroll
        for (int j = 0; j < 4; ++j) {
            bw[j] = bWall[(size_t)s * NG + j * 64 + hh];
            un[j] = ug[(size_t)(0 * NL + lq) * NG + j * 64 + hh];
        }
        bwd_r = bWd[(size_t)s * NH + hh];
    }
    __syncthreads();

    const int arow = lane & 15, akq = lane >> 4;
    const unsigned afrag0 = (unsigned)arow * RSTRIDE + akq * 8;          // ks=0
    const unsigned afrag1 = afrag0 + 32;                                  // ks=1
    for (int t = 0; t < NT; ++t) {
        // ---- phase 1: A-frags via plain ds_read_b128, MFMA, scatter C ----
        f16x8 ah[2], al[2];
        ah[0] = *(const f16x8*)&HSH[afrag0];
        ah[1] = *(const f16x8*)&HSH[afrag1];
        al[0] = *(const f16x8*)&HSL[afrag0];
        al[1] = *(const f16x8*)&HSL[afrag1];
        f16x8 cah[2], cal[2];
        if (wave < 4) {
            cah[0] = *(const f16x8*)&CSH[afrag0];
            cah[1] = *(const f16x8*)&CSH[afrag1];
            cal[0] = *(const f16x8*)&CSL[afrag0];
            cal[1] = *(const f16x8*)&CSL[afrag1];
        }
        #pragma unroll
        for (int t2 = 0; t2 < 3; ++t2) {
            if (t2 < nT) {
                const int tc = wave + t2 * 8;
                const bool isWd = (tc >= 16);
                f32x4 acc = {};
                #pragma unroll
                for (int ks = 0; ks < 2; ++ks) {
                    f16x8 A_h = isWd ? cah[ks] : ah[ks];
                    f16x8 A_l = isWd ? cal[ks] : al[ks];
                    acc = __builtin_amdgcn_mfma_f32_16x16x32_f16(A_h, Bh[t2][ks], acc, 0, 0, 0);
                    acc = __builtin_amdgcn_mfma_f32_16x16x32_f16(A_h, Bl[t2][ks], acc, 0, 0, 0);
                    acc = __builtin_amdgcn_mfma_f32_16x16x32_f16(A_l, Bh[t2][ks], acc, 0, 0, 0);
                }
                #pragma unroll
                for (int r = 0; r < 4; ++r) {
                    const int row = 4 * akq + r;
                    if (row < NL) {
                        if (!isWd) GATES[row * NG + tc * 16 + arow] = acc[r];
                        else       WDC[row * NH + (tc - 16) * 16 + arow] = acc[r];
                    }
                }
            }
        }
        float unx[4];
        if (tid < 320 && t + 1 < NT) {
            #pragma unroll
            for (int j = 0; j < 4; ++j)
                unx[j] = ug[(size_t)((t + 1) * NL + lq) * NG + j * 64 + hh];
        }
        __syncthreads();

        // ---- phase 2 (tid<320): activations + state update + SPLIT STORE ----
        if (tid < 320) {
            float g0 = GATES[lq * NG + hh]        + bw[0] + un[0];
            float g1 = GATES[lq * NG + 64 + hh]   + bw[1] + un[1];
            float g2 = GATES[lq * NG + 128 + hh]  + bw[2] + un[2];
            float g3 = GATES[lq * NG + 192 + hh]  + bw[3] + un[3];
            float f  = sigf(g0), ii = sigf(g1), oo = sigf(g2), ct = sigf(g3);
            float cs1 = tanhf(WDC[lq * NH + hh] + bwd_r);
            float ca  = c_reg - cs1 + cs1 * TSH[lq * NT + t];
            float cn  = f * ca + ii * ct;
            c_reg = cn;
            h_reg = oo * tanhf(cn);
            const unsigned sidx = (unsigned)lq * RSTRIDE + hh;
            U16 a, b;
            a.f = (__fp16)h_reg;            HSH[sidx] = a.s;
            b.f = (__fp16)(h_reg - (float)a.f); HSL[sidx] = b.s;
            a.f = (__fp16)cn;               CSH[sidx] = a.s;
            b.f = (__fp16)(cn - (float)a.f);   CSL[sidx] = b.s;
            ug[(size_t)(t * NL + lq) * NG + hh] = oo;   // o_t -> dead f-slot
            #pragma unroll
            for (int j = 0; j < 4; ++j) un[j] = unx[j];
        }
        __syncthreads();
    }
    if (tid < 320)
        ug[(size_t)(0 * NL + lq) * NG + 64 + hh] = h_reg;   // h_fin -> dead i-slot
}

// ---------------------------------------------------------------------------
// Kernel 2b (unchanged): attention + day LSTM + head. Measured 62.8 us.
// ---------------------------------------------------------------------------
#define P_W1    0
#define P_W2    4096
#define P_FULLO 8192
#define P_HS    14592
#define P_TQ    14912
#define P_CA    15232
#define P_SC    15552
#define P_B0    15652
#define P_B1    15716
#define P_BVV   15780
#define P_BV1   15844
#define P_TOT   15848

__global__ __launch_bounds__(320, 2) void k_post(
    const float* __restrict__ u,
    const float* __restrict__ W1, const float* __restrict__ b1,
    const float* __restrict__ W2, const float* __restrict__ b2,
    const float* __restrict__ V, const float* __restrict__ bV,
    const float* __restrict__ Wih, const float* __restrict__ bih,
    const float* __restrict__ bhh, const float* __restrict__ lin_w,
    const float* __restrict__ lin_b, float* __restrict__ out)
{
    __shared__ float sm[P_TOT];
    const int s = blockIdx.x;
    const int tid = threadIdx.x;
    const int lq = tid >> 6, hh = tid & 63;
    const int lane = hh;
    const float* ug = u + (size_t)s * NT * NL * NG;

    for (int i = tid; i < 1024; i += 320)
        *(float4*)&sm[P_W1 + i * 4] = *(const float4*)(W1 + (size_t)s * 4096 + i * 4);
    for (int i = tid; i < 1024; i += 320)
        *(float4*)&sm[P_W2 + i * 4] = *(const float4*)(W2 + (size_t)s * 4096 + i * 4);
    for (int i = tid; i < 1600; i += 320) {
        const int idx = i >> 4;
        const int l = idx / NT, t = idx % NT;
        const int k4 = (i & 15) * 4;
        *(float4*)&sm[P_FULLO + idx * NH + k4] =
            *(const float4*)(ug + (size_t)(t * NL + l) * NG + k4);
    }
    sm[P_HS + tid] = ug[(size_t)(0 * NL + lq) * NG + 64 + hh];
    if (tid < NH) {
        sm[P_B0 + tid]  = b1[(size_t)s * NH + tid];
        sm[P_B1 + tid]  = b2[(size_t)s * NH + tid];
        sm[P_BVV + tid] = V[(size_t)s * NH + tid];
    }
    if (tid == 0) sm[P_BV1] = bV[s];
    __syncthreads();

    {
        float qv = sm[P_B0 + hh];
        for (int k4 = 0; k4 < NH; k4 += 4) {
            float4 hv = *(const float4*)&sm[P_HS + lq * NH + k4];
            qv += hv.x * sm[P_W1 + (k4 + 0) * NH + hh]
                + hv.y * sm[P_W1 + (k4 + 1) * NH + hh]
                + hv.z * sm[P_W1 + (k4 + 2) * NH + hh]
                + hv.w * sm[P_W1 + (k4 + 3) * NH + hh];
        }
        sm[P_TQ + tid] = qv;
    }
    __syncthreads();

    for (int lt = lq; lt < NL * NT; lt += 5) {
        int l = lt / NT;
        float v = sm[P_TQ + l * NH + lane] + sm[P_B1 + lane];
        for (int k4 = 0; k4 < NH; k4 += 4) {
            float4 fv = *(const float4*)&sm[P_FULLO + lt * NH + k4];
            v += fv.x * sm[P_W2 + (k4 + 0) * NH + lane]
               + fv.y * sm[P_W2 + (k4 + 1) * NH + lane]
               + fv.z * sm[P_W2 + (k4 + 2) * NH + lane]
               + fv.w * sm[P_W2 + (k4 + 3) * NH + lane];
        }
        v = tanhf(v) * sm[P_BVV + lane];
        #pragma unroll
        for (int m = 32; m > 0; m >>= 1) v += __shfl_xor(v, m, 64);
        if (lane == 0) sm[P_SC + lt] = v + sm[P_BV1];
    }
    __syncthreads();

    if (tid < NL) {
        float mx = -1e30f;
        for (int t = 0; t < NT; ++t) mx = fmaxf(mx, sm[P_SC + tid * NT + t]);
        float sum = 0.0f;
        for (int t = 0; t < NT; ++t) {
            float e = expf(sm[P_SC + tid * NT + t] - mx);
            sm[P_SC + tid * NT + t] = e;
            sum += e;
        }
        float inv = 1.0f / sum;
        for (int t = 0; t < NT; ++t) sm[P_SC + tid * NT + t] *= inv;
    }
    __syncthreads();

    {
        float sv = 0.0f;
        #pragma unroll
        for (int t = 0; t < NT; ++t)
            sv += sm[P_SC + lq * NT + t] * sm[P_FULLO + (lq * NT + t) * NH + hh];
        sm[P_CA + tid] = sv;
    }
    __syncthreads();

    if (tid < NG) {
        float bsum = bih[(size_t)s * NG + tid] + bhh[(size_t)s * NG + tid];
        float d[NL];
        #pragma unroll
        for (int l = 0; l < NL; ++l) d[l] = bsum;
        for (int k = 0; k < NH; ++k) {
            float wk = Wih[((size_t)s * NH + k) * NG + tid];
            #pragma unroll
            for (int l = 0; l < NL; ++l)
                d[l] += sm[P_CA + l * NH + k] * wk;
        }
        #pragma unroll
        for (int l = 0; l < NL; ++l)
            sm[P_FULLO + l * NG + tid] = d[l];
    }
    __syncthreads();
    {
        float gi = sm[P_FULLO + lq * NG + hh];
        float gg = sm[P_FULLO + lq * NG + 128 + hh];
        float go = sm[P_FULLO + lq * NG + 192 + hh];
        float cd = sigf(gi) * tanhf(gg);
        sm[P_TQ + tid] = sigf(go) * tanhf(cd);
    }
    __syncthreads();

    {
        float v = sm[P_B0 + lane] + sm[P_B1 + lane];
        for (int k4 = 0; k4 < NH; k4 += 4) {
            float4 hv = *(const float4*)&sm[P_TQ + lq * NH + k4];
            v += hv.x * (sm[P_W1 + (k4 + 0) * NH + lane] + sm[P_W2 + (k4 + 0) * NH + lane])
               + hv.y * (sm[P_W1 + (k4 + 1) * NH + lane] + sm[P_W2 + (k4 + 1) * NH + lane])
               + hv.z * (sm[P_W1 + (k4 + 2) * NH + lane] + sm[P_W2 + (k4 + 2) * NH + lane])
               + hv.w * (sm[P_W1 + (k4 + 3) * NH + lane] + sm[P_W2 + (k4 + 3) * NH + lane]);
        }
        v = tanhf(v) * sm[P_BVV + lane];
        #pragma unroll
        for (int m = 32; m > 0; m >>= 1) v += __shfl_xor(v, m, 64);
        if (lane == 0) sm[P_SC + lq] = v + sm[P_BV1];
    }
    __syncthreads();
    if (tid == 0) {
        float mx = -1e30f;
        for (int l = 0; l < NL; ++l) mx = fmaxf(mx, sm[P_SC + l]);
        float sum = 0.0f;
        for (int l = 0; l < NL; ++l) {
            float e = expf(sm[P_SC + l] - mx);
            sm[P_SC + l] = e;
            sum += e;
        }
        float inv = 1.0f / sum;
        for (int l = 0; l < NL; ++l) sm[P_SC + l] *= inv;
    }
    __syncthreads();

    if (tid < NH) {
        float fv = 0.0f;
        #pragma unroll
        for (int l = 0; l < NL; ++l)
            fv += sm[P_SC + l] * sm[P_TQ + l * NH + tid];
        fv *= lin_w[tid];
        #pragma unroll
        for (int m = 32; m > 0; m >>= 1) fv += __shfl_xor(fv, m, 64);
        if (tid == 0) {
            float val = fv + lin_b[0];
            out[s] = val > 0.0f ? val : 0.01f * val;
        }
    }
}

extern "C" void kernel_launch(void* const* d_in, const int* in_sizes, int n_in,
                              void* d_out, int out_size, void* d_ws, size_t ws_size,
                              hipStream_t stream) {
    (void)in_sizes; (void)n_in; (void)out_size; (void)ws_size;
    const float* x     = (const float*)d_in[0];
    const float* ti    = (const float*)d_in[1];
    const float* Wall  = (const float*)d_in[2];
    const float* bWall = (const float*)d_in[3];
    const float* Uall  = (const float*)d_in[4];
    const float* bUall = (const float*)d_in[5];
    const float* Wd    = (const float*)d_in[6];
    const float* bWd   = (const float*)d_in[7];
    const float* W1    = (const float*)d_in[8];
    const float* b1    = (const float*)d_in[9];
    const float* W2    = (const float*)d_in[10];
    const float* b2    = (const float*)d_in[11];
    const float* V     = (const float*)d_in[12];
    const float* bV    = (const float*)d_in[13];
    const float* Wih   = (const float*)d_in[14];
    const float* bih   = (const float*)d_in[16];
    const float* bhh   = (const float*)d_in[17];
    const float* lin_w = (const float*)d_in[18];
    const float* lin_b = (const float*)d_in[19];
    float* out = (float*)d_out;
    float* u = (float*)d_ws;   // [S][T][L][NG] = 52.4 MB

    k_gemm_u<<<NS * 2, 512, 0, stream>>>(x, Uall, bUall, u);
    k_recur<<<NS, 512, 0, stream>>>(u, ti, Wall, bWall, Wd, bWd);
    k_post<<<NS, 320, 0, stream>>>(u, W1, b1, W2, b2, V, bV,
                                   Wih, bih, bhh, lin_w, lin_b, out);
}

// Round 16
// 788.260 us; speedup vs baseline: 1.3110x; 1.0552x over previous
//
#include <hip/hip_runtime.h>
#include <cstddef>

#define NS 512
#define NL 5
#define NT 20
#define NE 768
#define NH 64
#define NG 256   // 4*H
#define RSTRIDE 72

__device__ __forceinline__ float sigf(float x) { return 1.0f / (1.0f + expf(-x)); }

typedef __fp16 h16x2 __attribute__((ext_vector_type(2)));
typedef _Float16 f16x8 __attribute__((ext_vector_type(8)));
typedef __attribute__((ext_vector_type(4))) float f32x4;

union PkU { h16x2 h; unsigned u; };
union U16 { __fp16 f; unsigned short s; };

__device__ __forceinline__ void split_pk(float a, float b, unsigned& hi, unsigned& lo) {
    PkU H, L;
    H.h = __builtin_amdgcn_cvt_pkrtz(a, b);
    float ra = a - (float)H.h[0];
    float rb = b - (float)H.h[1];
    L.h = __builtin_amdgcn_cvt_pkrtz(ra, rb);
    hi = H.u; lo = L.u;
}

__device__ __forceinline__ void pack8(const float v[8], uint4& ph, uint4& pl) {
    split_pk(v[0], v[1], ph.x, pl.x);
    split_pk(v[2], v[3], ph.y, pl.y);
    split_pk(v[4], v[5], ph.z, pl.z);
    split_pk(v[6], v[7], ph.w, pl.w);
}

__device__ __forceinline__ void stage8(const float v[8], unsigned short* base, unsigned off) {
    uint4 ph, pl;
    pack8(v, ph, pl);
    *(uint4*)&base[off]       = ph;
    *(uint4*)&base[off + 512] = pl;
}

// ---------------------------------------------------------------------------
// Kernel 1 v7 (measured 129.3 us, ~95% of traffic floor; unchanged).
// ---------------------------------------------------------------------------
__global__ __launch_bounds__(512, 4) void k_gemm_u(
    const float* __restrict__ x, const float* __restrict__ U,
    const float* __restrict__ bU, float* __restrict__ u)
{
    __shared__ unsigned short Af[8 * 2 * 512];   // 16 KB
    __shared__ unsigned short Bf[8 * 2 * 512];   // 16 KB
    const int bid = blockIdx.x;
    const int s = bid >> 1, half = bid & 1;
    const int tid = threadIdx.x;
    const int wave = tid >> 6, lane = tid & 63;
    const int wm = wave & 1, wn = wave >> 1;
    const float* xg = x + (size_t)s * (NL * NT * NE);
    const float* Ug = U + (size_t)s * (NE * NG) + half * 128;

    f32x4 acc[4][2] = {};

    const int arow = tid >> 2, ab = tid & 3;
    const unsigned a_off = ((unsigned)(arow >> 4) * 2) * 512 + ((arow & 15) + 16 * ab) * 8;
    const int bcol = tid & 127, bkq = tid >> 7;
    const unsigned b_off = ((unsigned)(bcol >> 4) * 2) * 512 + ((bcol & 15) + 16 * bkq) * 8;

    float av[8], bv[8];
    {
        const float* pa = xg + (size_t)arow * NE + ab * 8;
        if (arow < 100) {
            float4 q0 = *(const float4*)pa, q1 = *(const float4*)(pa + 4);
            av[0]=q0.x; av[1]=q0.y; av[2]=q0.z; av[3]=q0.w;
            av[4]=q1.x; av[5]=q1.y; av[6]=q1.z; av[7]=q1.w;
        } else {
            #pragma unroll
            for (int j = 0; j < 8; ++j) av[j] = 0.0f;
        }
        #pragma unroll
        for (int j = 0; j < 8; ++j)
            bv[j] = Ug[(size_t)(8 * bkq + j) * NG + bcol];
    }

    for (int st = 0; st < 24; ++st) {
        stage8(av, Af, a_off);
        stage8(bv, Bf, b_off);
        __syncthreads();

        if (st + 1 < 24) {
            const int k0 = (st + 1) * 32;
            const float* pa = xg + (size_t)arow * NE + k0 + ab * 8;
            if (arow < 100) {
                float4 q0 = *(const float4*)pa, q1 = *(const float4*)(pa + 4);
                av[0]=q0.x; av[1]=q0.y; av[2]=q0.z; av[3]=q0.w;
                av[4]=q1.x; av[5]=q1.y; av[6]=q1.z; av[7]=q1.w;
            } else {
                #pragma unroll
                for (int j = 0; j < 8; ++j) av[j] = 0.0f;
            }
            #pragma unroll
            for (int j = 0; j < 8; ++j)
                bv[j] = Ug[(size_t)(k0 + 8 * bkq + j) * NG + bcol];
        }

        f16x8 bh[2], bl[2];
        #pragma unroll
        for (int ni = 0; ni < 2; ++ni) {
            const unsigned nt = wn * 2 + ni;
            bh[ni] = *(const f16x8*)&Bf[(nt * 2 + 0) * 512 + lane * 8];
            bl[ni] = *(const f16x8*)&Bf[(nt * 2 + 1) * 512 + lane * 8];
        }
        #pragma unroll
        for (int mi = 0; mi < 4; ++mi) {
            const unsigned mt = wm * 4 + mi;
            f16x8 ah = *(const f16x8*)&Af[(mt * 2 + 0) * 512 + lane * 8];
            f16x8 al = *(const f16x8*)&Af[(mt * 2 + 1) * 512 + lane * 8];
            #pragma unroll
            for (int ni = 0; ni < 2; ++ni) {
                acc[mi][ni] = __builtin_amdgcn_mfma_f32_16x16x32_f16(ah, bh[ni], acc[mi][ni], 0, 0, 0);
                acc[mi][ni] = __builtin_amdgcn_mfma_f32_16x16x32_f16(ah, bl[ni], acc[mi][ni], 0, 0, 0);
                acc[mi][ni] = __builtin_amdgcn_mfma_f32_16x16x32_f16(al, bh[ni], acc[mi][ni], 0, 0, 0);
            }
        }
        __syncthreads();
    }

    const int c_sub = 4 * (lane >> 4);
    #pragma unroll
    for (int ni = 0; ni < 2; ++ni) {
        const int gcol = half * 128 + (wn * 2 + ni) * 16 + (lane & 15);
        const float bb = bU[(size_t)s * NG + gcol];
        #pragma unroll
        for (int mi = 0; mi < 4; ++mi) {
            const int grow0 = wm * 64 + mi * 16 + c_sub;
            #pragma unroll
            for (int r = 0; r < 4; ++r) {
                const int grow = grow0 + r;
                if (grow < 100) {
                    const int ld = grow / 20, td = grow % 20;
                    u[(((size_t)s * NT + td) * NL + ld) * NG + gcol] = acc[mi][ni][r] + bb;
                }
            }
        }
    }
}

// ---------------------------------------------------------------------------
// Kernel 2 FUSED (recur v5 + post): one launch per stock. o-gates go to LDS
// FULLO (no u round-trip); h_fin to LDS; W1/W2 staged at kernel start so
// their fetch latency hides under the 20-step recurrence; one launch+drain
// boundary removed. Total LDS 79.4 KB -> still 2 blocks/CU. All arithmetic
// bit-identical to the split version (only transport changed).
// ---------------------------------------------------------------------------
__global__ __launch_bounds__(512, 4) void k_fused(
    const float* __restrict__ u, const float* __restrict__ ti,
    const float* __restrict__ Wall, const float* __restrict__ bWall,
    const float* __restrict__ Wd, const float* __restrict__ bWd,
    const float* __restrict__ W1, const float* __restrict__ b1,
    const float* __restrict__ W2, const float* __restrict__ b2,
    const float* __restrict__ V, const float* __restrict__ bV,
    const float* __restrict__ Wih, const float* __restrict__ bih,
    const float* __restrict__ bhh, const float* __restrict__ lin_w,
    const float* __restrict__ lin_b, float* __restrict__ out)
{
    __shared__ float FW1[4096];            // 16 KB
    __shared__ float FW2[4096];            // 16 KB
    __shared__ float FULLO[NL * NT * NH];  // 25.6 KB o-gates [l][t][h]
    __shared__ float GATES[NL * NG];       // 5 KB
    __shared__ float WDC[NL * NH];
    __shared__ float TSH[NL * NT];
    __shared__ float PHS[320];             // h_fin
    __shared__ float PTQ[320];             // q, later hd
    __shared__ float PCA[320];             // text_vec
    __shared__ float PSC[100];
    __shared__ float PB0[64], PB1[64], PBVV[64], PBV1[1];
    __shared__ unsigned short HSH[16 * RSTRIDE];
    __shared__ unsigned short HSL[16 * RSTRIDE];
    __shared__ unsigned short CSH[16 * RSTRIDE];
    __shared__ unsigned short CSL[16 * RSTRIDE];

    const int s = blockIdx.x;
    const int tid = threadIdx.x;
    const int wave = tid >> 6, lane = tid & 63;
    const float* ug = u + (size_t)s * NT * NL * NG;

    // ---- init: W1/W2 staging issues NOW, latency hides under recurrence ----
    for (int i = tid; i < 1024; i += 512)
        *(float4*)&FW1[i * 4] = *(const float4*)(W1 + (size_t)s * 4096 + i * 4);
    for (int i = tid; i < 1024; i += 512)
        *(float4*)&FW2[i * 4] = *(const float4*)(W2 + (size_t)s * 4096 + i * 4);
    for (int i = tid; i < 16 * RSTRIDE; i += 512) {
        HSH[i] = 0; HSL[i] = 0; CSH[i] = 0; CSL[i] = 0;
    }
    if (tid < NL * NT) TSH[tid] = ti[(size_t)s * NL * NT + tid];
    if (tid < NH) {
        PB0[tid]  = b1[(size_t)s * NH + tid];
        PB1[tid]  = b2[(size_t)s * NH + tid];
        PBVV[tid] = V[(size_t)s * NH + tid];
    }
    if (tid == 0) PBV1[0] = bV[s];

    // ---- B-fragments directly global -> registers (once) ----
    const int nT = (wave < 4) ? 3 : 2;
    f16x8 Bh[3][2], Bl[3][2];
    {
        const float* Wg = Wall + (size_t)s * (NH * NG);
        const float* Dg = Wd + (size_t)s * (NH * NH);
        const int fcol = lane & 15, foct = lane >> 4;
        #pragma unroll
        for (int t2 = 0; t2 < 3; ++t2) {
            if (t2 < nT) {
                const int tc = wave + t2 * 8;
                #pragma unroll
                for (int ks = 0; ks < 2; ++ks) {
                    float v[8];
                    if (tc < 16) {
                        #pragma unroll
                        for (int j = 0; j < 8; ++j)
                            v[j] = Wg[(size_t)(ks * 32 + foct * 8 + j) * NG + tc * 16 + fcol];
                    } else {
                        #pragma unroll
                        for (int j = 0; j < 8; ++j)
                            v[j] = Dg[(size_t)(ks * 32 + foct * 8 + j) * NH + (tc - 16) * 16 + fcol];
                    }
                    union { uint4 u4; f16x8 h8; } H, L;
                    pack8(v, H.u4, L.u4);
                    Bh[t2][ks] = H.h8;
                    Bl[t2][ks] = L.h8;
                }
            }
        }
    }

    // ---- consumer state (tid<320): (l,hh) item ----
    const int lq = tid >> 6, hh = tid & 63;
    const int lane64 = hh;
    float bw[4], bwd_r = 0.0f, un[4], c_reg = 0.0f, h_reg = 0.0f;
    if (tid < 320) {
        #pragma unroll
        for (int j = 0; j < 4; ++j) {
            bw[j] = bWall[(size_t)s * NG + j * 64 + hh];
            un[j] = ug[(size_t)(0 * NL + lq) * NG + j * 64 + hh];
        }
        bwd_r = bWd[(size_t)s * NH + hh];
    }
    __syncthreads();

    // ================= TimeLSTM recurrence =================
    const int arow = lane & 15, akq = lane >> 4;
    const unsigned afrag0 = (unsigned)arow * RSTRIDE + akq * 8;
    const unsigned afrag1 = afrag0 + 32;
    for (int t = 0; t < NT; ++t) {
        f16x8 ah[2], al[2];
        ah[0] = *(const f16x8*)&HSH[afrag0];
        ah[1] = *(const f16x8*)&HSH[afrag1];
        al[0] = *(const f16x8*)&HSL[afrag0];
        al[1] = *(const f16x8*)&HSL[afrag1];
        f16x8 cah[2], cal[2];
        if (wave < 4) {
            cah[0] = *(const f16x8*)&CSH[afrag0];
            cah[1] = *(const f16x8*)&CSH[afrag1];
            cal[0] = *(const f16x8*)&CSL[afrag0];
            cal[1] = *(const f16x8*)&CSL[afrag1];
        }
        #pragma unroll
        for (int t2 = 0; t2 < 3; ++t2) {
            if (t2 < nT) {
                const int tc = wave + t2 * 8;
                const bool isWd = (tc >= 16);
                f32x4 acc = {};
                #pragma unroll
                for (int ks = 0; ks < 2; ++ks) {
                    f16x8 A_h = isWd ? cah[ks] : ah[ks];
                    f16x8 A_l = isWd ? cal[ks] : al[ks];
                    acc = __builtin_amdgcn_mfma_f32_16x16x32_f16(A_h, Bh[t2][ks], acc, 0, 0, 0);
                    acc = __builtin_amdgcn_mfma_f32_16x16x32_f16(A_h, Bl[t2][ks], acc, 0, 0, 0);
                    acc = __builtin_amdgcn_mfma_f32_16x16x32_f16(A_l, Bh[t2][ks], acc, 0, 0, 0);
                }
                #pragma unroll
                for (int r = 0; r < 4; ++r) {
                    const int row = 4 * akq + r;
                    if (row < NL) {
                        if (!isWd) GATES[row * NG + tc * 16 + arow] = acc[r];
                        else       WDC[row * NH + (tc - 16) * 16 + arow] = acc[r];
                    }
                }
            }
        }
        float unx[4];
        if (tid < 320 && t + 1 < NT) {
            #pragma unroll
            for (int j = 0; j < 4; ++j)
                unx[j] = ug[(size_t)((t + 1) * NL + lq) * NG + j * 64 + hh];
        }
        __syncthreads();

        if (tid < 320) {
            float g0 = GATES[lq * NG + hh]        + bw[0] + un[0];
            float g1 = GATES[lq * NG + 64 + hh]   + bw[1] + un[1];
            float g2 = GATES[lq * NG + 128 + hh]  + bw[2] + un[2];
            float g3 = GATES[lq * NG + 192 + hh]  + bw[3] + un[3];
            float f  = sigf(g0), ii = sigf(g1), oo = sigf(g2), ct = sigf(g3);
            float cs1 = tanhf(WDC[lq * NH + hh] + bwd_r);
            float ca  = c_reg - cs1 + cs1 * TSH[lq * NT + t];
            float cn  = f * ca + ii * ct;
            c_reg = cn;
            h_reg = oo * tanhf(cn);
            const unsigned sidx = (unsigned)lq * RSTRIDE + hh;
            U16 a, b;
            a.f = (__fp16)h_reg;               HSH[sidx] = a.s;
            b.f = (__fp16)(h_reg - (float)a.f); HSL[sidx] = b.s;
            a.f = (__fp16)cn;                  CSH[sidx] = a.s;
            b.f = (__fp16)(cn - (float)a.f);   CSL[sidx] = b.s;
            FULLO[(lq * NT + t) * NH + hh] = oo;       // o_t -> LDS (no HBM)
            #pragma unroll
            for (int j = 0; j < 4; ++j) un[j] = unx[j];
        }
        __syncthreads();
    }
    if (tid < 320) PHS[tid] = h_reg;                   // h_fin -> LDS
    __syncthreads();

    // ================= attention + day LSTM + head =================
    // q = h_fin @ W1 + b1 (tid<320)
    if (tid < 320) {
        float qv = PB0[hh];
        for (int k4 = 0; k4 < NH; k4 += 4) {
            float4 hv = *(const float4*)&PHS[lq * NH + k4];
            qv += hv.x * FW1[(k4 + 0) * NH + hh]
                + hv.y * FW1[(k4 + 1) * NH + hh]
                + hv.z * FW1[(k4 + 2) * NH + hh]
                + hv.w * FW1[(k4 + 3) * NH + hh];
        }
        PTQ[tid] = qv;
    }
    __syncthreads();

    // scores: 100 (l,t) items over 8 waves
    for (int lt = wave; lt < NL * NT; lt += 8) {
        int l = lt / NT;
        float v = PTQ[l * NH + lane64] + PB1[lane64];
        for (int k4 = 0; k4 < NH; k4 += 4) {
            float4 fv = *(const float4*)&FULLO[lt * NH + k4];
            v += fv.x * FW2[(k4 + 0) * NH + lane64]
               + fv.y * FW2[(k4 + 1) * NH + lane64]
               + fv.z * FW2[(k4 + 2) * NH + lane64]
               + fv.w * FW2[(k4 + 3) * NH + lane64];
        }
        v = tanhf(v) * PBVV[lane64];
        #pragma unroll
        for (int m = 32; m > 0; m >>= 1) v += __shfl_xor(v, m, 64);
        if (lane64 == 0) PSC[lt] = v + PBV1[0];
    }
    __syncthreads();

    // softmax over t per l
    if (tid < NL) {
        float mx = -1e30f;
        for (int t = 0; t < NT; ++t) mx = fmaxf(mx, PSC[tid * NT + t]);
        float sum = 0.0f;
        for (int t = 0; t < NT; ++t) {
            float e = expf(PSC[tid * NT + t] - mx);
            PSC[tid * NT + t] = e;
            sum += e;
        }
        float inv = 1.0f / sum;
        for (int t = 0; t < NT; ++t) PSC[tid * NT + t] *= inv;
    }
    __syncthreads();

    // text_vec -> PCA
    if (tid < 320) {
        float sv = 0.0f;
        #pragma unroll
        for (int t = 0; t < NT; ++t)
            sv += PSC[lq * NT + t] * FULLO[(lq * NT + t) * NH + hh];
        PCA[tid] = sv;
    }
    __syncthreads();

    // day LSTM: gates alias dead FULLO region
    if (tid < NG) {
        float bsum = bih[(size_t)s * NG + tid] + bhh[(size_t)s * NG + tid];
        float d[NL];
        #pragma unroll
        for (int l = 0; l < NL; ++l) d[l] = bsum;
        for (int k = 0; k < NH; ++k) {
            float wk = Wih[((size_t)s * NH + k) * NG + tid];
            #pragma unroll
            for (int l = 0; l < NL; ++l)
                d[l] += PCA[l * NH + k] * wk;
        }
        #pragma unroll
        for (int l = 0; l < NL; ++l)
            FULLO[l * NG + tid] = d[l];
    }
    __syncthreads();
    if (tid < 320) {
        float gi = FULLO[lq * NG + hh];
        float gg = FULLO[lq * NG + 128 + hh];
        float go = FULLO[lq * NG + 192 + hh];
        float cd = sigf(gi) * tanhf(gg);
        PTQ[tid] = sigf(go) * tanhf(cd);    // hd (q dead)
    }
    __syncthreads();

    // day attention: wave lq handles l=lq (<5)
    if (lq < NL) {
        float v = PB0[lane64] + PB1[lane64];
        for (int k4 = 0; k4 < NH; k4 += 4) {
            float4 hv = *(const float4*)&PTQ[lq * NH + k4];
            v += hv.x * (FW1[(k4 + 0) * NH + lane64] + FW2[(k4 + 0) * NH + lane64])
               + hv.y * (FW1[(k4 + 1) * NH + lane64] + FW2[(k4 + 1) * NH + lane64])
               + hv.z * (FW1[(k4 + 2) * NH + lane64] + FW2[(k4 + 2) * NH + lane64])
               + hv.w * (FW1[(k4 + 3) * NH + lane64] + FW2[(k4 + 3) * NH + lane64]);
        }
        v = tanhf(v) * PBVV[lane64];
        #pragma unroll
        for (int m = 32; m > 0; m >>= 1) v += __shfl_xor(v, m, 64);
        if (lane64 == 0) PSC[lq] = v + PBV1[0];
    }
    __syncthreads();
    if (tid == 0) {
        float mx = -1e30f;
        for (int l = 0; l < NL; ++l) mx = fmaxf(mx, PSC[l]);
        float sum = 0.0f;
        for (int l = 0; l < NL; ++l) {
            float e = expf(PSC[l] - mx);
            PSC[l] = e;
            sum += e;
        }
        float inv = 1.0f / sum;
        for (int l = 0; l < NL; ++l) PSC[l] *= inv;
    }
    __syncthreads();

    if (tid < NH) {
        float fv = 0.0f;
        #pragma unroll
        for (int l = 0; l < NL; ++l)
            fv += PSC[l] * PTQ[l * NH + tid];
        fv *= lin_w[tid];
        #pragma unroll
        for (int m = 32; m > 0; m >>= 1) fv += __shfl_xor(fv, m, 64);
        if (tid == 0) {
            float val = fv + lin_b[0];
            out[s] = val > 0.0f ? val : 0.01f * val;
        }
    }
}

extern "C" void kernel_launch(void* const* d_in, const int* in_sizes, int n_in,
                              void* d_out, int out_size, void* d_ws, size_t ws_size,
                              hipStream_t stream) {
    (void)in_sizes; (void)n_in; (void)out_size; (void)ws_size;
    const float* x     = (const float*)d_in[0];
    const float* ti    = (const float*)d_in[1];
    const float* Wall  = (const float*)d_in[2];
    const float* bWall = (const float*)d_in[3];
    const float* Uall  = (const float*)d_in[4];
    const float* bUall = (const float*)d_in[5];
    const float* Wd    = (const float*)d_in[6];
    const float* bWd   = (const float*)d_in[7];
    const float* W1    = (const float*)d_in[8];
    const float* b1    = (const float*)d_in[9];
    const float* W2    = (const float*)d_in[10];
    const float* b2    = (const float*)d_in[11];
    const float* V     = (const float*)d_in[12];
    const float* bV    = (const float*)d_in[13];
    const float* Wih   = (const float*)d_in[14];
    const float* bih   = (const float*)d_in[16];
    const float* bhh   = (const float*)d_in[17];
    const float* lin_w = (const float*)d_in[18];
    const float* lin_b = (const float*)d_in[19];
    float* out = (float*)d_out;
    float* u = (float*)d_ws;   // [S][T][L][NG] = 52.4 MB

    k_gemm_u<<<NS * 2, 512, 0, stream>>>(x, Uall, bUall, u);
    k_fused<<<NS, 512, 0, stream>>>(u, ti, Wall, bWall, Wd, bWd,
                                    W1, b1, W2, b2, V, bV,
                                    Wih, bih, bhh, lin_w, lin_b, out);
}